// Round 3
// baseline (568.629 us; speedup 1.0000x reference)
//
#include <hip/hip_runtime.h>
#include <hip/hip_bf16.h>

// EdgewiseReduce: out[n, :] = sum_{e : dst[e]==n} edge_data[e, :] * 0.5
// E = 1.6M, D = 32, N = 100K.
//
// Round 1: 51.2M f32 global atomics -> 819 MB of 16B txns, 647 us.
// Round 2: counting sort. Scatter of 4B ids -> 106 MB of 64B-line
//          writebacks (every sub-line global scatter is ~16x amplified).
// Round 3: LDS privatization, single kernel. 256 blocks; block b owns
// nodes [b*391, b*391+391) as a 50 KB LDS accumulator (row stride 33
// floats to decorrelate banks: bank = (d*33+j)%32 = (d+j)%32, random d
// -> ~2-way, free). Each block scans ALL dsts with int4 loads; matches
// are wave-ballot-compacted into a per-wave LDS queue (no block syncs);
// queue flushes load the 128B row once and ds_add_f32 into the
// accumulator. One coalesced float4 writeout. No global atomics, no
// global scatter, no memset.

#define D 32
#define FACTOR 0.5f
#define BLOCK_THREADS 1024
#define NWAVES (BLOCK_THREADS / 64)
#define QCAP 96        // flush threshold 32, max add/step 64 -> max 95

__device__ __forceinline__ void flush_queue(
    const float4* __restrict__ data, float* acc,
    const int* q_e, const int* q_d, int wq, int qcount, int lane, int lo) {
  for (int s = 0; s < qcount; s += 64) {
    int mcnt = qcount - s;
    if (mcnt > 64) mcnt = 64;
    if (lane < mcnt) {
      int e = q_e[wq + s + lane];
      int d = q_d[wq + s + lane];
      const float4* rp = data + (size_t)e * 8;
      float4 v0 = rp[0], v1 = rp[1], v2 = rp[2], v3 = rp[3];
      float4 v4 = rp[4], v5 = rp[5], v6 = rp[6], v7 = rp[7];
      float* a = acc + (d - lo) * 33;
      atomicAdd(a + 0,  v0.x); atomicAdd(a + 1,  v0.y);
      atomicAdd(a + 2,  v0.z); atomicAdd(a + 3,  v0.w);
      atomicAdd(a + 4,  v1.x); atomicAdd(a + 5,  v1.y);
      atomicAdd(a + 6,  v1.z); atomicAdd(a + 7,  v1.w);
      atomicAdd(a + 8,  v2.x); atomicAdd(a + 9,  v2.y);
      atomicAdd(a + 10, v2.z); atomicAdd(a + 11, v2.w);
      atomicAdd(a + 12, v3.x); atomicAdd(a + 13, v3.y);
      atomicAdd(a + 14, v3.z); atomicAdd(a + 15, v3.w);
      atomicAdd(a + 16, v4.x); atomicAdd(a + 17, v4.y);
      atomicAdd(a + 18, v4.z); atomicAdd(a + 19, v4.w);
      atomicAdd(a + 20, v5.x); atomicAdd(a + 21, v5.y);
      atomicAdd(a + 22, v5.z); atomicAdd(a + 23, v5.w);
      atomicAdd(a + 24, v6.x); atomicAdd(a + 25, v6.y);
      atomicAdd(a + 26, v6.z); atomicAdd(a + 27, v6.w);
      atomicAdd(a + 28, v7.x); atomicAdd(a + 29, v7.y);
      atomicAdd(a + 30, v7.z); atomicAdd(a + 31, v7.w);
    }
  }
}

__device__ __forceinline__ int4 load_dst4(const int* __restrict__ dst,
                                          const int4* __restrict__ dst4,
                                          int idx4, int E4, int E) {
  int4 dv = make_int4(-1, -1, -1, -1);
  if (idx4 < E4) {
    int ebase = idx4 << 2;
    if (ebase + 3 < E) {
      dv = dst4[idx4];
    } else {
      dv.x = dst[ebase];
      if (ebase + 1 < E) dv.y = dst[ebase + 1];
      if (ebase + 2 < E) dv.z = dst[ebase + 2];
    }
  }
  return dv;
}

__global__ __launch_bounds__(BLOCK_THREADS)
void EdgewiseReduce_64776696758368_kernel(
    const float4* __restrict__ data,   // [E, 8] float4
    const int* __restrict__ dst,       // [E]
    float4* __restrict__ out,          // [N, 8] float4
    int E, int N, int npb) {
  extern __shared__ float smem[];
  float* acc = smem;                                   // [npb * 33]
  int* q_e = (int*)(smem + (size_t)npb * 33);          // [NWAVES * QCAP]
  int* q_d = q_e + NWAVES * QCAP;                      // [NWAVES * QCAP]

  const int lane = threadIdx.x & 63;
  const int w = threadIdx.x >> 6;
  const int lo = blockIdx.x * npb;
  const int hi = min(lo + npb, N);
  const unsigned long long lmask_lt = (1ull << lane) - 1ull;
  const int wq = w * QCAP;
  const int4* dst4 = (const int4*)dst;

  // Zero the accumulator.
  const int accn = npb * 33;
  for (int i = threadIdx.x; i < accn; i += BLOCK_THREADS) acc[i] = 0.f;
  __syncthreads();

  const int E4 = (E + 3) >> 2;
  const int iters = (E4 + BLOCK_THREADS - 1) / BLOCK_THREADS;
  int qcount = 0;

  // Software-pipelined scan: load iteration it+1 while processing it.
  int4 dv = load_dst4(dst, dst4, w * 64 + lane, E4, E);
  for (int it = 0; it < iters; ++it) {
    int ebase = (it * BLOCK_THREADS + w * 64 + lane) << 2;
    int4 cur = dv;
    dv = load_dst4(dst, dst4, (it + 1) * BLOCK_THREADS + w * 64 + lane, E4, E);

    int dc[4] = {cur.x, cur.y, cur.z, cur.w};
    bool m0 = (dc[0] >= lo) & (dc[0] < hi);
    bool m1 = (dc[1] >= lo) & (dc[1] < hi);
    bool m2 = (dc[2] >= lo) & (dc[2] < hi);
    bool m3 = (dc[3] >= lo) & (dc[3] < hi);
    if (__ballot(m0 | m1 | m2 | m3) == 0ull) continue;   // fast path

    bool mm[4] = {m0, m1, m2, m3};
    #pragma unroll
    for (int c = 0; c < 4; ++c) {
      unsigned long long mask = __ballot(mm[c]);
      if (mm[c]) {
        int pos = qcount + __popcll(mask & lmask_lt);
        q_e[wq + pos] = ebase + c;
        q_d[wq + pos] = dc[c];
      }
      qcount += __popcll(mask);
      if (qcount >= 32) {                 // wave-uniform
        flush_queue(data, acc, q_e, q_d, wq, qcount, lane, lo);
        qcount = 0;
      }
    }
  }
  if (qcount > 0) flush_queue(data, acc, q_e, q_d, wq, qcount, lane, lo);

  __syncthreads();

  // Coalesced writeout, scale by FACTOR here.
  const int nlocal = hi - lo;
  const int total4 = nlocal * 8;
  for (int i = threadIdx.x; i < total4; i += BLOCK_THREADS) {
    int r = i >> 3, jq = i & 7;
    const float* a = acc + r * 33 + jq * 4;
    float4 v;
    v.x = a[0] * FACTOR; v.y = a[1] * FACTOR;
    v.z = a[2] * FACTOR; v.w = a[3] * FACTOR;
    out[(size_t)(lo + r) * 8 + jq] = v;
  }
}

// ---------- Fallback: round-1 atomic scatter (if LDS doesn't fit) ----------
__global__ void atomic_kernel(const float4* __restrict__ edge_data,
                              const int* __restrict__ edge_dst,
                              float* __restrict__ out, int E, int N) {
  int tid = blockIdx.x * blockDim.x + threadIdx.x;
  int e = tid >> 3;
  int q = tid & 7;
  if (e >= E) return;
  int dst = edge_dst[e];
  if (dst < 0 || dst >= N) return;
  float4 v = edge_data[(size_t)e * 8 + q];
  float* p = out + (size_t)dst * D + q * 4;
  unsafeAtomicAdd(p + 0, v.x * FACTOR);
  unsafeAtomicAdd(p + 1, v.y * FACTOR);
  unsafeAtomicAdd(p + 2, v.z * FACTOR);
  unsafeAtomicAdd(p + 3, v.w * FACTOR);
}

extern "C" void kernel_launch(void* const* d_in, const int* in_sizes, int n_in,
                              void* d_out, int out_size, void* d_ws, size_t ws_size,
                              hipStream_t stream) {
  const float4* edge_data = (const float4*)d_in[0];
  const int* edge_dst = (const int*)d_in[1];

  int E = in_sizes[1];
  int N = out_size / D;

  int nblocks = 256;
  int npb = (N + nblocks - 1) / nblocks;           // 391 for N=100K
  size_t smem = (size_t)npb * 33 * sizeof(float)
              + (size_t)2 * NWAVES * QCAP * sizeof(int);  // 63,900 B

  if (smem > 65536) {
    // Fallback: pure atomic scatter.
    float* out = (float*)d_out;
    hipMemsetAsync(d_out, 0, (size_t)out_size * sizeof(float), stream);
    int total = E * 8;
    atomic_kernel<<<(total + 255) / 256, 256, 0, stream>>>(edge_data, edge_dst, out, E, N);
    return;
  }

  EdgewiseReduce_64776696758368_kernel<<<nblocks, BLOCK_THREADS, smem, stream>>>(
      edge_data, edge_dst, (float4*)d_out, E, N, npb);
}